// Round 3
// baseline (107.123 us; speedup 1.0000x reference)
//
#include <hip/hip_runtime.h>
#include <math.h>

#define N 256
#define D 512
#define SPLIT 4
#define NTILE 8                    // 256/32 tiles per side
#define NUPPER (NTILE * (NTILE + 1) / 2)   // 36
#define KROW 68                    // padded LDS row (floats); 272B, 16B-aligned

__device__ __forceinline__ float smooth_l1(float x) {
    float ax = fabsf(x);
    return ax < 1.f ? 0.5f * ax * ax : ax - 0.5f;
}

__device__ __forceinline__ float dot4(float4 a, float4 b) {
    return a.x * b.x + a.y * b.y + a.z * b.z + a.w * b.w;
}

// ---------------------------------------------------------------------------
// Symmetric Gram: G = E * E^T.  32x32 tiles, upper-triangular tile set only,
// mirrored writes.  2x2 outputs/thread -> 4x less LDS read traffic per FLOP.
// grid (36, 1, 2), block 256.  Block (0,_,0) zero-inits acc + counter.
// ---------------------------------------------------------------------------
__global__ __launch_bounds__(256) void gram_kernel(const float* __restrict__ Es,
                                                   const float* __restrict__ Et,
                                                   float* __restrict__ Gs,
                                                   float* __restrict__ Gt,
                                                   float* __restrict__ acc) {
    const float* E = blockIdx.z ? Et : Es;
    float* G = blockIdx.z ? Gt : Gs;
    const int t = threadIdx.x;

    if (blockIdx.x == 0 && blockIdx.z == 0 && t == 0) {
        acc[0] = 0.f;                       // dist sum
        acc[1] = 0.f;                       // angle sum
        *(unsigned int*)&acc[2] = 0u;       // completion counter
    }

    // tile index -> (bi, bj), bi <= bj
    int bi = 0, rem = blockIdx.x;
    while (rem >= NTILE - bi) { rem -= NTILE - bi; ++bi; }
    const int bj = bi + rem;

    __shared__ __align__(16) float As[32 * KROW];
    __shared__ __align__(16) float Bs[32 * KROW];

    const int tx = t & 15, ty = t >> 4;
    float s00 = 0.f, s01 = 0.f, s10 = 0.f, s11 = 0.f;

    for (int k0 = 0; k0 < D; k0 += 64) {
        // stage 32x64 panels; thread loads slots t and t+256 (row=s>>4, col4=s&15)
#pragma unroll
        for (int s = t; s < 512; s += 256) {
            const int r = s >> 4, c = (s & 15) * 4;
            *(float4*)&As[r * KROW + c] = *(const float4*)&E[(bi * 32 + r) * D + k0 + c];
            *(float4*)&Bs[r * KROW + c] = *(const float4*)&E[(bj * 32 + r) * D + k0 + c];
        }
        __syncthreads();
        const float4* A0 = (const float4*)&As[ty * KROW];
        const float4* A1 = (const float4*)&As[(ty + 16) * KROW];
        const float4* B0 = (const float4*)&Bs[tx * KROW];
        const float4* B1 = (const float4*)&Bs[(tx + 16) * KROW];
#pragma unroll
        for (int kk = 0; kk < 16; ++kk) {
            float4 a0 = A0[kk], a1 = A1[kk], b0 = B0[kk], b1 = B1[kk];
            s00 += dot4(a0, b0);
            s01 += dot4(a0, b1);
            s10 += dot4(a1, b0);
            s11 += dot4(a1, b1);
        }
        __syncthreads();
    }

    const int r0 = bi * 32 + ty, r1 = r0 + 16;
    const int c0 = bj * 32 + tx, c1 = c0 + 16;
    G[r0 * N + c0] = s00;  G[c0 * N + r0] = s00;
    G[r0 * N + c1] = s01;  G[c1 * N + r0] = s01;
    G[r1 * N + c0] = s10;  G[c0 * N + r1] = s10;
    G[r1 * N + c1] = s11;  G[c1 * N + r1] = s11;
}

// ---------------------------------------------------------------------------
// Fused angle + distance loss + finalize (last block writes d_out).
// grid (255, SPLIT), block 256.  j = blockIdx.x + 1.
// Gram recombination: dot = G[i,k] - G[i,j] - G[k,j] + G[j,j];
//                     |e_a-e_j|^2 = G[a,a] - 2 G[a,j] + G[j,j].
// eps_pd correction (~2e-6 on loss) dropped; eps_cos floor unreachable.
// ---------------------------------------------------------------------------
__global__ __launch_bounds__(256) void angle_dist_kernel(const float* __restrict__ Gs,
                                                         const float* __restrict__ Gt,
                                                         float* __restrict__ acc,
                                                         float* __restrict__ out) {
    const int j = blockIdx.x + 1;   // 1..255
    const int tid = threadIdx.x;
    __shared__ float2 sv[N], tv[N];   // (G[a,j], 1/|e_a - e_j|) per matrix
    __shared__ float2 red[256];
    const float Gsjj = Gs[j * N + j];
    const float Gtjj = Gt[j * N + j];

    float distp = 0.f;
    {
        const int a = tid;
        float cja = Gs[a * N + j];
        float cjb = Gt[a * N + j];
        float n2s = Gs[a * N + a] - 2.f * cja + Gsjj;
        float n2t = Gt[a * N + a] - 2.f * cjb + Gtjj;
        float rs = (a == j) ? 0.f : rsqrtf(n2s);
        float rt = (a == j) ? 0.f : rsqrtf(n2t);
        sv[a] = make_float2(cja, rs);
        tv[a] = make_float2(cjb, rt);
        if (blockIdx.y == 0 && a < j)
            distp = smooth_l1(n2s * rs - n2t * rt);   // sqrt(x) = x * rsqrt(x)
    }
    __syncthreads();

    const int nk = 255 - j;          // k in [j+1, 255]
    const int npairs = j * nk;       // i in [0, j)
    const float inv_nk = 1.0f / (float)nk;
    const float lo = -0.99999994f;   // -(1 - 1e-7)
    const float hi = 0.99999994f;

    float anglep = 0.f;
    for (int p = blockIdx.y * 256 + tid; p < npairs; p += 256 * SPLIT) {
        int i = (int)((float)p * inv_nk);
        int rem = p - i * nk;
        if (rem < 0) { --i; rem += nk; }
        else if (rem >= nk) { ++i; rem -= nk; }
        const int k = j + 1 + rem;
        float2 si = sv[i], sk = sv[k];
        float2 ti = tv[i], tk = tv[k];
        float dots = Gs[i * N + k] - si.x - sk.x + Gsjj;
        float dott = Gt[i * N + k] - ti.x - tk.x + Gtjj;
        float coss = fminf(fmaxf(dots * (si.y * sk.y), lo), hi);
        float cost = fminf(fmaxf(dott * (ti.y * tk.y), lo), hi);
        anglep += smooth_l1(acosf(coss) - acosf(cost));
    }

    red[tid] = make_float2(distp, anglep);
    __syncthreads();
    for (int s = 128; s > 0; s >>= 1) {
        if (tid < s) {
            red[tid].x += red[tid + s].x;
            red[tid].y += red[tid + s].y;
        }
        __syncthreads();
    }
    if (tid == 0) {
        atomicAdd(&acc[1], red[0].y);
        if (blockIdx.y == 0) atomicAdd(&acc[0], red[0].x);
        __threadfence();
        unsigned int old = atomicAdd((unsigned int*)&acc[2], 1u);
        if (old == (N - 1) * SPLIT - 1) {
            // last block: all prior atomics to acc are visible (fence + atomic RMW)
            float ds = atomicAdd(&acc[0], 0.f);
            float as = atomicAdd(&acc[1], 0.f);
            float dl = 2.f * ds / (float)(N * N);
            float al = as / (float)(N * (N - 1) * (N - 2) / 6);
            out[0] = 1.0f * dl + 2.0f * al;
            out[1] = dl;
            out[2] = al;
        }
    }
}

extern "C" void kernel_launch(void* const* d_in, const int* in_sizes, int n_in,
                              void* d_out, int out_size, void* d_ws, size_t ws_size,
                              hipStream_t stream) {
    const float* Es = (const float*)d_in[0];
    const float* Et = (const float*)d_in[1];
    float* out = (float*)d_out;
    float* ws = (float*)d_ws;

    float* acc = ws;              // [0]=dist, [1]=angle, [2]=counter (as uint)
    float* Gs  = ws + 64;
    float* Gt  = Gs + N * N;

    gram_kernel<<<dim3(NUPPER, 1, 2), 256, 0, stream>>>(Es, Et, Gs, Gt, acc);
    angle_dist_kernel<<<dim3(N - 1, SPLIT), 256, 0, stream>>>(Gs, Gt, acc, out);
}

// Round 4
// 94.705 us; speedup vs baseline: 1.1311x; 1.1311x over previous
//
#include <hip/hip_runtime.h>
#include <math.h>

#define N 256
#define D 512
#define SPLIT 4
#define KROW 68   // padded LDS row (floats): 272B, 16B-aligned, conflict-free b128

__device__ __forceinline__ float smooth_l1(float x) {
    float ax = fabsf(x);
    return ax < 1.f ? 0.5f * ax * ax : ax - 0.5f;
}

__device__ __forceinline__ float dot4(float4 a, float4 b) {
    return a.x * b.x + a.y * b.y + a.z * b.z + a.w * b.w;
}

// ---------------------------------------------------------------------------
// Gram: G = E * E^T.  32x32 tiles, 2x2 outputs/thread (4x less LDS read
// traffic per FLOP than 16x16/1-out).  grid (8,8,2), block 256.  All writes
// coalesced; no symmetry mirror (scattered 4B column writes cost more than
// the redundant compute saves — measured R3).  Block (0,0,0) zeroes acc.
// NOTE: no device-scope fences anywhere hot — R3's per-block __threadfence
// finalize cost ~+20us (L2 writeback storm across XCDs).
// ---------------------------------------------------------------------------
__global__ __launch_bounds__(256) void gram_kernel(const float* __restrict__ Es,
                                                   const float* __restrict__ Et,
                                                   float* __restrict__ Gs,
                                                   float* __restrict__ Gt,
                                                   float* __restrict__ acc) {
    const float* E = blockIdx.z ? Et : Es;
    float* G = blockIdx.z ? Gt : Gs;
    const int t = threadIdx.x;

    if (blockIdx.x == 0 && blockIdx.y == 0 && blockIdx.z == 0 && t == 0) {
        acc[0] = 0.f;   // dist sum
        acc[1] = 0.f;   // angle sum
    }

    const int bi = blockIdx.y, bj = blockIdx.x;
    __shared__ __align__(16) float As[32 * KROW];
    __shared__ __align__(16) float Bs[32 * KROW];

    const int tx = t & 15, ty = t >> 4;
    float s00 = 0.f, s01 = 0.f, s10 = 0.f, s11 = 0.f;

    for (int k0 = 0; k0 < D; k0 += 64) {
        // stage two 32x64 panels; thread fills slots t and t+256
#pragma unroll
        for (int s = t; s < 512; s += 256) {
            const int r = s >> 4, c = (s & 15) * 4;
            *(float4*)&As[r * KROW + c] = *(const float4*)&E[(bi * 32 + r) * D + k0 + c];
            *(float4*)&Bs[r * KROW + c] = *(const float4*)&E[(bj * 32 + r) * D + k0 + c];
        }
        __syncthreads();
        const float4* A0 = (const float4*)&As[ty * KROW];
        const float4* A1 = (const float4*)&As[(ty + 16) * KROW];
        const float4* B0 = (const float4*)&Bs[tx * KROW];
        const float4* B1 = (const float4*)&Bs[(tx + 16) * KROW];
#pragma unroll
        for (int kk = 0; kk < 16; ++kk) {
            float4 a0 = A0[kk], a1 = A1[kk], b0 = B0[kk], b1 = B1[kk];
            s00 += dot4(a0, b0);
            s01 += dot4(a0, b1);
            s10 += dot4(a1, b0);
            s11 += dot4(a1, b1);
        }
        __syncthreads();
    }

    const int r0 = bi * 32 + ty, r1 = r0 + 16;
    const int c0 = bj * 32 + tx, c1 = c0 + 16;
    G[r0 * N + c0] = s00;
    G[r0 * N + c1] = s01;
    G[r1 * N + c0] = s10;
    G[r1 * N + c1] = s11;
}

// ---------------------------------------------------------------------------
// Fused angle + distance loss.  grid (255, SPLIT), block 256.  j = bx + 1.
// Gram recombination: dot = G[i,k] - G[i,j] - G[k,j] + G[j,j];
//                     |e_a-e_j|^2 = G[a,a] - 2 G[a,j] + G[j,j].
// eps_pd correction (~2e-6 on loss) dropped; eps_cos floor unreachable.
// ---------------------------------------------------------------------------
__global__ __launch_bounds__(256) void angle_dist_kernel(const float* __restrict__ Gs,
                                                         const float* __restrict__ Gt,
                                                         float* __restrict__ acc) {
    const int j = blockIdx.x + 1;   // 1..255
    const int tid = threadIdx.x;
    __shared__ float2 sv[N], tv[N];   // (G[a,j], 1/|e_a - e_j|) per matrix
    __shared__ float2 red[256];
    const float Gsjj = Gs[j * N + j];
    const float Gtjj = Gt[j * N + j];

    float distp = 0.f;
    {
        const int a = tid;
        float cja = Gs[a * N + j];
        float cjb = Gt[a * N + j];
        float n2s = Gs[a * N + a] - 2.f * cja + Gsjj;
        float n2t = Gt[a * N + a] - 2.f * cjb + Gtjj;
        float rs = (a == j) ? 0.f : rsqrtf(n2s);
        float rt = (a == j) ? 0.f : rsqrtf(n2t);
        sv[a] = make_float2(cja, rs);
        tv[a] = make_float2(cjb, rt);
        if (blockIdx.y == 0 && a < j)
            distp = smooth_l1(n2s * rs - n2t * rt);   // sqrt(x) = x * rsqrt(x)
    }
    __syncthreads();

    const int nk = 255 - j;          // k in [j+1, 255]
    const int npairs = j * nk;       // i in [0, j)
    const float inv_nk = 1.0f / (float)nk;
    const float lo = -0.99999994f;   // -(1 - 1e-7)
    const float hi = 0.99999994f;

    float anglep = 0.f;
    for (int p = blockIdx.y * 256 + tid; p < npairs; p += 256 * SPLIT) {
        int i = (int)((float)p * inv_nk);
        int rem = p - i * nk;
        if (rem < 0) { --i; rem += nk; }
        else if (rem >= nk) { ++i; rem -= nk; }
        const int k = j + 1 + rem;
        float2 si = sv[i], sk = sv[k];
        float2 ti = tv[i], tk = tv[k];
        float dots = Gs[i * N + k] - si.x - sk.x + Gsjj;
        float dott = Gt[i * N + k] - ti.x - tk.x + Gtjj;
        float coss = fminf(fmaxf(dots * (si.y * sk.y), lo), hi);
        float cost = fminf(fmaxf(dott * (ti.y * tk.y), lo), hi);
        anglep += smooth_l1(acosf(coss) - acosf(cost));
    }

    red[tid] = make_float2(distp, anglep);
    __syncthreads();
    for (int s = 128; s > 0; s >>= 1) {
        if (tid < s) {
            red[tid].x += red[tid + s].x;
            red[tid].y += red[tid + s].y;
        }
        __syncthreads();
    }
    if (tid == 0) {
        atomicAdd(&acc[1], red[0].y);
        if (blockIdx.y == 0) atomicAdd(&acc[0], red[0].x);
    }
}

__global__ void finalize_kernel(const float* __restrict__ acc,
                                float* __restrict__ out) {
    float dl = 2.f * acc[0] / (float)(N * N);                 // mean over full n x n
    float al = acc[1] / (float)(N * (N - 1) * (N - 2) / 6);   // C(n,3) triplets
    out[0] = 1.0f * dl + 2.0f * al;
    out[1] = dl;
    out[2] = al;
}

extern "C" void kernel_launch(void* const* d_in, const int* in_sizes, int n_in,
                              void* d_out, int out_size, void* d_ws, size_t ws_size,
                              hipStream_t stream) {
    const float* Es = (const float*)d_in[0];
    const float* Et = (const float*)d_in[1];
    float* out = (float*)d_out;
    float* ws = (float*)d_ws;

    float* acc = ws;              // [0]=dist, [1]=angle
    float* Gs  = ws + 64;
    float* Gt  = Gs + N * N;

    gram_kernel<<<dim3(8, 8, 2), 256, 0, stream>>>(Es, Et, Gs, Gt, acc);
    angle_dist_kernel<<<dim3(N - 1, SPLIT), 256, 0, stream>>>(Gs, Gt, acc);
    finalize_kernel<<<1, 1, 0, stream>>>(acc, out);
}

// Round 5
// 86.219 us; speedup vs baseline: 1.2425x; 1.0984x over previous
//
#include <hip/hip_runtime.h>
#include <math.h>

#define N 256
#define D 512
#define SPLIT 4

using f32x4  = __attribute__((ext_vector_type(4))) float;
using bf16x8 = __attribute__((ext_vector_type(8))) short;

// round-to-nearest-even f32 -> bf16 bits (inputs finite)
__device__ __forceinline__ short f2bf(float f) {
    unsigned u = __float_as_uint(f);
    u += 0x7fffu + ((u >> 16) & 1u);
    return (short)(u >> 16);
}

__device__ __forceinline__ float smooth_l1(float x) {
    float ax = fabsf(x);
    return ax < 1.f ? 0.5f * ax * ax : ax - 0.5f;
}

// A&S 4.4.45: |err| <= 5e-5 on [-1,1]; loss threshold is 1.47e-2 -> safe.
__device__ __forceinline__ float acos_fast(float x) {
    float ax = fabsf(x);
    float p = -0.0187293f;
    p = p * ax + 0.0742610f;
    p = p * ax - 0.2121144f;
    p = p * ax + 1.5707288f;
    float v = sqrtf(1.f - ax) * p;
    return x < 0.f ? 3.14159265358979f - v : v;
}

// ---------------------------------------------------------------------------
// MFMA Gram: G = E * E^T via bf16 16x16x32 matrix cores. One wave per 16x16
// output tile, grid (16,16,2) [z: 0=student,1=teacher], block 64 (1 wave).
// No LDS: operands loaded直接 from L2-resident E in the verified A-operand
// layout A[m=lane&15][k=(lane>>4)*8 + j] (same pattern as verified QK^T,
// m118-m122); C/D layout col=lane&15, row=(lane>>4)*4+reg (verified m89/m91).
// G stored interleaved float2 (x=student, y=teacher) so the angle kernel's
// hot loop does one b64 load per triplet instead of two b32.
// bf16 cast error on the final losses ~1e-3 << 1.47e-2 threshold.
// ---------------------------------------------------------------------------
__global__ __launch_bounds__(64) void gram_kernel(const float* __restrict__ Es,
                                                  const float* __restrict__ Et,
                                                  float2* __restrict__ G2,
                                                  float* __restrict__ acc) {
    const int lane = threadIdx.x;
    if (blockIdx.x == 0 && blockIdx.y == 0 && blockIdx.z == 0 && lane == 0) {
        acc[0] = 0.f;   // dist sum
        acc[1] = 0.f;   // angle sum
    }
    const float* E = blockIdx.z ? Et : Es;
    const int m = lane & 15, quad = lane >> 4;
    const int baseA = (blockIdx.y * 16 + m) * D + quad * 8;
    const int baseB = (blockIdx.x * 16 + m) * D + quad * 8;

    f32x4 c = {0.f, 0.f, 0.f, 0.f};
#pragma unroll
    for (int k0 = 0; k0 < D; k0 += 32) {
        float4 alo = *(const float4*)&E[baseA + k0];
        float4 ahi = *(const float4*)&E[baseA + k0 + 4];
        float4 blo = *(const float4*)&E[baseB + k0];
        float4 bhi = *(const float4*)&E[baseB + k0 + 4];
        bf16x8 a, b;
        a[0] = f2bf(alo.x); a[1] = f2bf(alo.y); a[2] = f2bf(alo.z); a[3] = f2bf(alo.w);
        a[4] = f2bf(ahi.x); a[5] = f2bf(ahi.y); a[6] = f2bf(ahi.z); a[7] = f2bf(ahi.w);
        b[0] = f2bf(blo.x); b[1] = f2bf(blo.y); b[2] = f2bf(blo.z); b[3] = f2bf(blo.w);
        b[4] = f2bf(bhi.x); b[5] = f2bf(bhi.y); b[6] = f2bf(bhi.z); b[7] = f2bf(bhi.w);
        c = __builtin_amdgcn_mfma_f32_16x16x32_bf16(a, b, c, 0, 0, 0);
    }

    const int col = blockIdx.x * 16 + m;
#pragma unroll
    for (int r = 0; r < 4; ++r) {
        const int row = blockIdx.y * 16 + quad * 4 + r;
        float* slot = (float*)&G2[row * N + col];
        slot[blockIdx.z] = c[r];
    }
}

// ---------------------------------------------------------------------------
// Fused angle + distance loss.  grid (255, SPLIT), block 256.  j = bx + 1.
// dot = G[i,k] - G[i,j] - G[k,j] + G[j,j];  |e_a-e_j|^2 = G[a,a]-2G[a,j]+G[j,j].
// eps_pd correction (~2e-6 on loss) dropped; eps_cos floor unreachable.
// No device-scope fences here (R3: per-block __threadfence cost ~+20us).
// ---------------------------------------------------------------------------
__global__ __launch_bounds__(256) void angle_dist_kernel(const float2* __restrict__ G2,
                                                         float* __restrict__ acc) {
    const int j = blockIdx.x + 1;   // 1..255
    const int tid = threadIdx.x;
    __shared__ float2 sv[N], tv[N];   // (G[a,j], 1/|e_a-e_j|) student / teacher
    __shared__ float2 red[256];
    const float2 gjj = G2[j * N + j];
    const float Gsjj = gjj.x, Gtjj = gjj.y;

    float distp = 0.f;
    {
        const int a = tid;
        float2 gaj = G2[a * N + j];
        float2 gaa = G2[a * N + a];
        float n2s = gaa.x - 2.f * gaj.x + Gsjj;
        float n2t = gaa.y - 2.f * gaj.y + Gtjj;
        float rs = (a == j) ? 0.f : rsqrtf(n2s);
        float rt = (a == j) ? 0.f : rsqrtf(n2t);
        sv[a] = make_float2(gaj.x, rs);
        tv[a] = make_float2(gaj.y, rt);
        if (blockIdx.y == 0 && a < j)
            distp = smooth_l1(n2s * rs - n2t * rt);   // sqrt(x) = x * rsqrt(x)
    }
    __syncthreads();

    const int nk = 255 - j;          // k in [j+1, 255]
    const int npairs = j * nk;       // i in [0, j)
    const float inv_nk = 1.0f / (float)nk;
    const float lo = -0.99999994f;
    const float hi = 0.99999994f;

    float anglep = 0.f;
    for (int p = blockIdx.y * 256 + tid; p < npairs; p += 256 * SPLIT) {
        int i = (int)((float)p * inv_nk);
        int rem = p - i * nk;
        if (rem < 0) { --i; rem += nk; }
        else if (rem >= nk) { ++i; rem -= nk; }
        const int k = j + 1 + rem;
        float2 si = sv[i], sk = sv[k];
        float2 ti = tv[i], tk = tv[k];
        float2 gik = G2[i * N + k];
        float dots = gik.x - si.x - sk.x + Gsjj;
        float dott = gik.y - ti.x - tk.x + Gtjj;
        float coss = fminf(fmaxf(dots * (si.y * sk.y), lo), hi);
        float cost = fminf(fmaxf(dott * (ti.y * tk.y), lo), hi);
        anglep += smooth_l1(acos_fast(coss) - acos_fast(cost));
    }

    red[tid] = make_float2(distp, anglep);
    __syncthreads();
    for (int s = 128; s > 0; s >>= 1) {
        if (tid < s) {
            red[tid].x += red[tid + s].x;
            red[tid].y += red[tid + s].y;
        }
        __syncthreads();
    }
    if (tid == 0) {
        atomicAdd(&acc[1], red[0].y);
        if (blockIdx.y == 0) atomicAdd(&acc[0], red[0].x);
    }
}

__global__ void finalize_kernel(const float* __restrict__ acc,
                                float* __restrict__ out) {
    float dl = 2.f * acc[0] / (float)(N * N);                 // mean over full n x n
    float al = acc[1] / (float)(N * (N - 1) * (N - 2) / 6);   // C(n,3) triplets
    out[0] = 1.0f * dl + 2.0f * al;
    out[1] = dl;
    out[2] = al;
}

extern "C" void kernel_launch(void* const* d_in, const int* in_sizes, int n_in,
                              void* d_out, int out_size, void* d_ws, size_t ws_size,
                              hipStream_t stream) {
    const float* Es = (const float*)d_in[0];
    const float* Et = (const float*)d_in[1];
    float* out = (float*)d_out;
    float* ws = (float*)d_ws;

    float* acc = ws;                      // [0]=dist, [1]=angle
    float2* G2 = (float2*)(ws + 64);      // N*N float2 (x=student, y=teacher)

    gram_kernel<<<dim3(16, 16, 2), 64, 0, stream>>>(Es, Et, G2, acc);
    angle_dist_kernel<<<dim3(N - 1, SPLIT), 256, 0, stream>>>(G2, acc);
    finalize_kernel<<<1, 1, 0, stream>>>(acc, out);
}